// Round 1
// baseline (2424.622 us; speedup 1.0000x reference)
//
#include <hip/hip_runtime.h>
#include <math.h>

#define B_    2
#define T_    2048
#define C_    512
#define NB_   4
#define HALF_ 256
#define BT_   (B_*T_)
#define EPS_  1.1920929e-07f
#define SQRT_C 22.627416997969522f

#define TT   16
#define ST   64
#define NPH  4

// ---------------- RoPE cos/sin tables ----------------
__global__ __launch_bounds__(256) void rope_table_k(float* __restrict__ cosT,
                                                    float* __restrict__ sinT) {
    int t = blockIdx.x;          // 0..2047
    int i = threadIdx.x;         // 0..255
    float ex   = (float)i / (float)HALF_;
    float invf = 1.0f / powf(10000.0f, ex);
    float ang  = (float)t * invf;
    float sv, cv;
    sincosf(ang, &sv, &cv);
    cosT[t*HALF_ + i] = cv;
    sinT[t*HALF_ + i] = sv;
}

// ---------------- generic fp32 GEMM, 64x64 tile ----------------
// C(MxN) = A(MxK) @ B(KxN), all row-major. M%64==0, N%64==0, K%16==0.
__global__ __launch_bounds__(256) void sgemm64_k(const float* __restrict__ A,
                                                 const float* __restrict__ B,
                                                 float* __restrict__ C,
                                                 int M, int N, int K) {
    __shared__ float As[16][64];
    __shared__ float Bs[16][64];
    int tid = threadIdx.x;
    int nb = N >> 6;
    int bx = blockIdx.x % nb, by = blockIdx.x / nb;
    int m0 = by << 6, n0 = bx << 6;
    int tx = tid & 15, ty = tid >> 4;
    int ar = tid >> 2, ac = (tid & 3) << 2;
    float acc[4][4] = {};
    for (int k0 = 0; k0 < K; k0 += 16) {
        float4 av = *(const float4*)(A + (size_t)(m0 + ar) * K + k0 + ac);
        As[ac+0][ar] = av.x; As[ac+1][ar] = av.y; As[ac+2][ar] = av.z; As[ac+3][ar] = av.w;
        float4 bv = *(const float4*)(B + (size_t)(k0 + ty) * N + n0 + (tx << 2));
        *(float4*)&Bs[ty][tx << 2] = bv;
        __syncthreads();
        #pragma unroll
        for (int kk = 0; kk < 16; kk++) {
            float4 a  = *(const float4*)&As[kk][ty << 2];
            float4 b4 = *(const float4*)&Bs[kk][tx << 2];
            acc[0][0] += a.x*b4.x; acc[0][1] += a.x*b4.y; acc[0][2] += a.x*b4.z; acc[0][3] += a.x*b4.w;
            acc[1][0] += a.y*b4.x; acc[1][1] += a.y*b4.y; acc[1][2] += a.y*b4.z; acc[1][3] += a.y*b4.w;
            acc[2][0] += a.z*b4.x; acc[2][1] += a.z*b4.y; acc[2][2] += a.z*b4.z; acc[2][3] += a.z*b4.w;
            acc[3][0] += a.w*b4.x; acc[3][1] += a.w*b4.y; acc[3][2] += a.w*b4.z; acc[3][3] += a.w*b4.w;
        }
        __syncthreads();
    }
    #pragma unroll
    for (int i = 0; i < 4; i++) {
        float4 o = make_float4(acc[i][0], acc[i][1], acc[i][2], acc[i][3]);
        *(float4*)(C + (size_t)(m0 + (ty<<2) + i) * N + n0 + (tx<<2)) = o;
    }
}

// ---------------- RMSNorm + RoPE on Q rows (in place) ----------------
// grid = BT_*NB_ blocks, 256 threads; Q layout rows (b*T+t), cols (n*C + c)
__global__ __launch_bounds__(256) void q_post_k(float* __restrict__ Q,
                                                const float* __restrict__ cosT,
                                                const float* __restrict__ sinT) {
    int blk = blockIdx.x;
    int n  = blk & 3;
    int bt = blk >> 2;
    int t  = bt & (T_ - 1);
    float* row = Q + (size_t)bt * (NB_*C_) + n * C_;
    int i = threadIdx.x;
    float x1 = row[i], x2 = row[i + HALF_];
    __shared__ float red[256];
    red[i] = x1*x1 + x2*x2;
    __syncthreads();
    for (int s = 128; s > 0; s >>= 1) {
        if (i < s) red[i] += red[i + s];
        __syncthreads();
    }
    float mean = red[0] * (1.0f / (float)C_);
    float r = rsqrtf(mean + EPS_);
    float xn1 = x1 * r, xn2 = x2 * r;
    float cv = cosT[t*HALF_ + i], sv = sinT[t*HALF_ + i];
    row[i]         = xn1*cv - xn2*sv;
    row[i + HALF_] = xn2*cv + xn1*sv;
}

// ---------------- RoPE on K rows (in place) ----------------
__global__ __launch_bounds__(256) void k_post_k(float* __restrict__ K,
                                                const float* __restrict__ cosT,
                                                const float* __restrict__ sinT) {
    int bt = blockIdx.x;
    int t  = bt & (T_ - 1);
    float* row = K + (size_t)bt * C_;
    int i = threadIdx.x;
    float x1 = row[i], x2 = row[i + HALF_];
    float cv = cosT[t*HALF_ + i], sv = sinT[t*HALF_ + i];
    row[i]         = x1*cv - x2*sv;
    row[i + HALF_] = x2*cv + x1*sv;
}

// ---------------- fused attention (partial over s-phases) ----------------
// block = (b, tt, phase): 16 t-rows, all 4 branches, s-tiles s0 = (phase + 4k)*64
__global__ __launch_bounds__(256) void attn_partial_k(
    const float* __restrict__ Q,   // (B*T) x (NB*C), post norm+rope
    const float* __restrict__ K,   // (B*T) x C, post rope
    const float* __restrict__ V,   // (B*T) x (NB*C)
    float* __restrict__ part_y,    // [B*128*NPH][TT*C]
    float* __restrict__ part_S,    // [B*128*NPH][TT]
    unsigned* __restrict__ part_act) // [B*128*NPH][TT]
{
    __shared__ float As[16][64];
    __shared__ float Bs[16][64];
    __shared__ float wuS[TT][ST + 1];
    __shared__ unsigned bitS[TT][ST + 1];
    __shared__ float yL[TT][520];          // padded 512 -> 520
    __shared__ float redS[TT][17];
    __shared__ unsigned redA[TT][17];
    __shared__ float Srun[TT];
    __shared__ unsigned Arun[TT];

    int tid = threadIdx.x;
    int blk = blockIdx.x;                  // = ((b*128 + tt)*NPH + phase)
    int phase = blk & (NPH - 1);
    int tt    = (blk >> 2) & 127;
    int b     = blk >> 9;
    int tx = tid & 15, ty = tid >> 4;
    int t0 = tt * TT;
    int tglob = t0 + ty;
    int tmax = t0 + TT - 1;

    for (int i = tid; i < TT*520; i += 256) ((float*)yL)[i] = 0.f;
    if (tid < TT) { Srun[tid] = 0.f; Arun[tid] = 0u; }
    __syncthreads();

    // staging roles (same for As and Bs)
    int ar = tid >> 2;               // 0..63
    int ac = (tid & 3) << 2;         // 0,4,8,12
    int atl = ar >> 2, an = ar & 3;  // q row decomposition
    const float* qptr = Q + (size_t)(b*T_ + t0 + atl) * (NB_*C_) + an*C_ + ac;

    for (int s0 = phase * ST; s0 <= tmax; s0 += NPH * ST) {
        // ---- att tile: rows (t_loc*4+n), cols s, inner c ----
        float facc[4][4] = {};
        int srow = s0 + ar; if (srow > T_ - 1) srow = T_ - 1;   // clamp (masked anyway)
        const float* kptr = K + (size_t)(b*T_ + srow) * C_ + ac;
        for (int k0 = 0; k0 < C_; k0 += 16) {
            float4 av = *(const float4*)(qptr + k0);
            As[ac+0][ar] = av.x; As[ac+1][ar] = av.y; As[ac+2][ar] = av.z; As[ac+3][ar] = av.w;
            float4 kv = *(const float4*)(kptr + k0);
            Bs[ac+0][ar] = kv.x; Bs[ac+1][ar] = kv.y; Bs[ac+2][ar] = kv.z; Bs[ac+3][ar] = kv.w;
            __syncthreads();
            #pragma unroll
            for (int kk = 0; kk < 16; kk++) {
                float4 a  = *(const float4*)&As[kk][ty << 2];
                float4 b4 = *(const float4*)&Bs[kk][tx << 2];
                facc[0][0] += a.x*b4.x; facc[0][1] += a.x*b4.y; facc[0][2] += a.x*b4.z; facc[0][3] += a.x*b4.w;
                facc[1][0] += a.y*b4.x; facc[1][1] += a.y*b4.y; facc[1][2] += a.y*b4.z; facc[1][3] += a.y*b4.w;
                facc[2][0] += a.z*b4.x; facc[2][1] += a.z*b4.y; facc[2][2] += a.z*b4.z; facc[2][3] += a.z*b4.w;
                facc[3][0] += a.w*b4.x; facc[3][1] += a.w*b4.y; facc[3][2] += a.w*b4.z; facc[3][3] += a.w*b4.w;
            }
            __syncthreads();
        }

        // ---- routing: thread owns (t = t0+ty, s = s0 + tx*4 + j), all 4 branches ----
        float wusum = 0.f; unsigned actor = 0u;
        #pragma unroll
        for (int j = 0; j < 4; j++) {
            int sg = s0 + (tx << 2) + j;
            float wu = 0.f; unsigned bits = 0u;
            if (sg <= tglob) {
                float a0 = facc[0][j] / SQRT_C;
                float a1 = facc[1][j] / SQRT_C;
                float a2 = facc[2][j] / SQRT_C;
                float a3 = facc[3][j] / SQRT_C;
                float m = fmaxf(fmaxf(a0, a1), fmaxf(a2, a3));
                float e0 = expf(a0 - m), e1 = expf(a1 - m), e2 = expf(a2 - m), e3 = expf(a3 - m);
                float sum = ((e0 + e1) + e2) + e3;               // sequential like np
                float p0 = e0/sum, p1 = e1/sum, p2 = e2/sum, p3 = e3/sum;
                float mp = fmaxf(fmaxf(p0, p1), fmaxf(p2, p3));
                bits = (p0 == mp ? 1u : 0u) | (p1 == mp ? 2u : 0u)
                     | (p2 == mp ? 4u : 0u) | (p3 == mp ? 8u : 0u);
                wu = fmaxf(m, 0.f) + log1pf(expf(-fabsf(m)));     // softplus(scores_max)
                wusum += wu; actor |= bits;
            }
            wuS[ty][(tx << 2) + j] = wu;
            bitS[ty][(tx << 2) + j] = bits;
        }
        redS[ty][tx] = wusum;
        redA[ty][tx] = actor;
        __syncthreads();
        if (tid < TT) {
            float ssum = 0.f; unsigned aor = 0u;
            #pragma unroll
            for (int i = 0; i < 16; i++) { ssum += redS[tid][i]; aor |= redA[tid][i]; }
            Srun[tid] += ssum; Arun[tid] |= aor;
        }

        // ---- context accumulate: yL[t][c] += wu * V[s][n][c] for active branches ----
        const float* vbase = V + (size_t)(b*T_ + s0) * (NB_*C_);
        for (int ss = 0; ss < ST; ss++) {
            unsigned bits = bitS[ty][ss];
            if (!bits) continue;                   // masked (s>t): zero weight
            float wu = wuS[ty][ss];
            const float* vrow = vbase + (size_t)ss * (NB_*C_);
            #pragma unroll
            for (int n = 0; n < 4; n++) if ((bits >> n) & 1u) {
                const float* vr = vrow + n*C_ + (tx << 1);
                float* yp = &yL[ty][tx << 1];
                #pragma unroll
                for (int ch = 0; ch < 16; ch++) {
                    float2 vv = *(const float2*)(vr + (ch << 5));
                    yp[(ch << 5) + 0] += wu * vv.x;
                    yp[(ch << 5) + 1] += wu * vv.y;
                }
            }
        }
        __syncthreads();
    }

    // ---- write partials (always, even if zero tiles ran) ----
    for (int i = tid; i < TT*C_; i += 256) {
        int t = i >> 9, c = i & (C_ - 1);
        part_y[(size_t)blk * (TT*C_) + i] = yL[t][c];
    }
    if (tid < TT) {
        part_S[(size_t)blk * TT + tid] = Srun[tid];
        part_act[(size_t)blk * TT + tid] = Arun[tid];
    }
}

// ---------------- combine phases + sinks -> Y ----------------
__global__ __launch_bounds__(256) void combine_k(
    const float* __restrict__ part_y, const float* __restrict__ part_S,
    const unsigned* __restrict__ part_act,
    const float* __restrict__ basis,      // (NB, C)
    const float* __restrict__ resid_sink, // (C)
    float* __restrict__ Y)                // (B*T, C)
{
    int bt = blockIdx.x;
    int t = bt & (T_ - 1);
    int tt = t >> 4, tl = t & 15;
    int b = bt >> 11;
    int i = threadIdx.x;
    int base_blk = (b * 128 + tt) * NPH;
    float S = 0.f; unsigned act = 0u;
    float y0 = 0.f, y1 = 0.f;
    for (int ph = 0; ph < NPH; ph++) {
        int pb = base_blk + ph;
        S   += part_S[(size_t)pb * TT + tl];
        act |= part_act[(size_t)pb * TT + tl];
        y0  += part_y[(size_t)pb * (TT*C_) + tl*C_ + i];
        y1  += part_y[(size_t)pb * (TT*C_) + tl*C_ + i + 256];
    }
    float scale = fminf(1.0f / (S + 1e-6f), 1.0f);
    float residual = 1.0f - scale * S;
    if (t < T_ - 1) act = 0xFu;     // masked cols force route_mask=1 on every branch
    float o0 = scale * y0, o1 = scale * y1;
    #pragma unroll
    for (int n = 0; n < 4; n++) if ((act >> n) & 1u) {
        o0 += basis[n*C_ + i];
        o1 += basis[n*C_ + i + 256];
    }
    o0 += residual * resid_sink[i];
    o1 += residual * resid_sink[i + 256];
    Y[(size_t)bt * C_ + i]       = o0;
    Y[(size_t)bt * C_ + i + 256] = o1;
}

extern "C" void kernel_launch(void* const* d_in, const int* in_sizes, int n_in,
                              void* d_out, int out_size, void* d_ws, size_t ws_size,
                              hipStream_t stream) {
    const float* a    = (const float*)d_in[0];
    const float* x    = (const float*)d_in[1];
    const float* Wq   = (const float*)d_in[2];
    const float* Wk   = (const float*)d_in[3];
    const float* Wv   = (const float*)d_in[4];
    const float* Wo   = (const float*)d_in[5];
    const float* vres = (const float*)d_in[6];
    const float* vbas = (const float*)d_in[7];

    float* ws   = (float*)d_ws;
    float* cosT = ws;
    float* sinT = cosT + (size_t)T_*HALF_;
    float* Q    = sinT + (size_t)T_*HALF_;
    float* K    = Q + (size_t)BT_*NB_*C_;
    float* V    = K + (size_t)BT_*C_;
    float* Yb   = V + (size_t)BT_*NB_*C_;
    float* py   = Yb + (size_t)BT_*C_;
    float* pS   = py + (size_t)(B_*128*NPH) * (TT*C_);
    unsigned* pA = (unsigned*)(pS + (size_t)(B_*128*NPH) * TT);

    rope_table_k<<<T_, 256, 0, stream>>>(cosT, sinT);
    sgemm64_k<<<(BT_/64)*((NB_*C_)/64), 256, 0, stream>>>(a, Wq, Q, BT_, NB_*C_, C_);
    sgemm64_k<<<(BT_/64)*((NB_*C_)/64), 256, 0, stream>>>(a, Wv, V, BT_, NB_*C_, C_);
    sgemm64_k<<<(BT_/64)*(C_/64),       256, 0, stream>>>(x, Wk, K, BT_, C_, C_);
    q_post_k<<<BT_*NB_, 256, 0, stream>>>(Q, cosT, sinT);
    k_post_k<<<BT_,     256, 0, stream>>>(K, cosT, sinT);
    attn_partial_k<<<B_*128*NPH, 256, 0, stream>>>(Q, K, V, py, pS, pA);
    combine_k<<<BT_, 256, 0, stream>>>(py, pS, pA, vbas, vres, Yb);
    sgemm64_k<<<(BT_/64)*(C_/64), 256, 0, stream>>>(Yb, Wo, (float*)d_out, BT_, C_, C_);
}

// Round 2
// 774.114 us; speedup vs baseline: 3.1321x; 3.1321x over previous
//
#include <hip/hip_runtime.h>
#include <math.h>

#define B_    2
#define T_    2048
#define C_    512
#define NB_   4
#define HALF_ 256
#define BT_   (B_*T_)
#define EPS_  1.1920929e-07f
#define SQRT_C 22.627416997969522f

#define TT2  32
#define ST2  64
#define NPH2 4
#define NBLK_ATTN (B_*(T_/TT2)*NPH2)   // 512

using f32x4 = __attribute__((ext_vector_type(4))) float;
using s16x8 = __attribute__((ext_vector_type(8))) short;
using u16x8 = __attribute__((ext_vector_type(8))) unsigned short;

__device__ __forceinline__ unsigned short f2bf(float f) {
    unsigned x = __float_as_uint(f);
    unsigned r = (x + 0x7fffu + ((x >> 16) & 1u)) >> 16;
    return (unsigned short)r;
}
__device__ __forceinline__ float bf2f(unsigned short h) {
    return __uint_as_float(((unsigned)h) << 16);
}

// ---------------- RoPE cos/sin tables ----------------
__global__ __launch_bounds__(256) void rope_table_k(float* __restrict__ cosT,
                                                    float* __restrict__ sinT) {
    int t = blockIdx.x;
    int i = threadIdx.x;
    float ex   = (float)i / (float)HALF_;
    float invf = 1.0f / powf(10000.0f, ex);
    float ang  = (float)t * invf;
    float sv, cv;
    sincosf(ang, &sv, &cv);
    cosT[t*HALF_ + i] = cv;
    sinT[t*HALF_ + i] = sv;
}

// ---------------- generic fp32 GEMM, 64x64 tile ----------------
__global__ __launch_bounds__(256) void sgemm64_k(const float* __restrict__ A,
                                                 const float* __restrict__ Bm,
                                                 float* __restrict__ Cm,
                                                 int M, int N, int K) {
    __shared__ float As[16][64];
    __shared__ float Bs[16][64];
    int tid = threadIdx.x;
    int nb = N >> 6;
    int bx = blockIdx.x % nb, by = blockIdx.x / nb;
    int m0 = by << 6, n0 = bx << 6;
    int tx = tid & 15, ty = tid >> 4;
    int ar = tid >> 2, ac = (tid & 3) << 2;
    float acc[4][4] = {};
    for (int k0 = 0; k0 < K; k0 += 16) {
        float4 av = *(const float4*)(A + (size_t)(m0 + ar) * K + k0 + ac);
        As[ac+0][ar] = av.x; As[ac+1][ar] = av.y; As[ac+2][ar] = av.z; As[ac+3][ar] = av.w;
        float4 bv = *(const float4*)(Bm + (size_t)(k0 + ty) * N + n0 + (tx << 2));
        *(float4*)&Bs[ty][tx << 2] = bv;
        __syncthreads();
        #pragma unroll
        for (int kk = 0; kk < 16; kk++) {
            float4 a  = *(const float4*)&As[kk][ty << 2];
            float4 b4 = *(const float4*)&Bs[kk][tx << 2];
            acc[0][0] += a.x*b4.x; acc[0][1] += a.x*b4.y; acc[0][2] += a.x*b4.z; acc[0][3] += a.x*b4.w;
            acc[1][0] += a.y*b4.x; acc[1][1] += a.y*b4.y; acc[1][2] += a.y*b4.z; acc[1][3] += a.y*b4.w;
            acc[2][0] += a.z*b4.x; acc[2][1] += a.z*b4.y; acc[2][2] += a.z*b4.z; acc[2][3] += a.z*b4.w;
            acc[3][0] += a.w*b4.x; acc[3][1] += a.w*b4.y; acc[3][2] += a.w*b4.z; acc[3][3] += a.w*b4.w;
        }
        __syncthreads();
    }
    #pragma unroll
    for (int i = 0; i < 4; i++) {
        float4 o = make_float4(acc[i][0], acc[i][1], acc[i][2], acc[i][3]);
        *(float4*)(Cm + (size_t)(m0 + (ty<<2) + i) * N + n0 + (tx<<2)) = o;
    }
}

// ---------------- RMSNorm + RoPE on Q rows -> Qhi/Qlo bf16 ----------------
__global__ __launch_bounds__(256) void q_post2_k(const float* __restrict__ Qf,
                                                 const float* __restrict__ cosT,
                                                 const float* __restrict__ sinT,
                                                 unsigned short* __restrict__ Qhi,
                                                 unsigned short* __restrict__ Qlo) {
    int blk = blockIdx.x;
    int n  = blk & 3;
    int bt = blk >> 2;
    int t  = bt & (T_ - 1);
    const float* row = Qf + (size_t)bt * (NB_*C_) + n * C_;
    int i = threadIdx.x;
    float x1 = row[i], x2 = row[i + HALF_];
    __shared__ float red[256];
    red[i] = x1*x1 + x2*x2;
    __syncthreads();
    for (int s = 128; s > 0; s >>= 1) {
        if (i < s) red[i] += red[i + s];
        __syncthreads();
    }
    float mean = red[0] * (1.0f / (float)C_);
    float r = rsqrtf(mean + EPS_);
    float xn1 = x1 * r, xn2 = x2 * r;
    float cv = cosT[t*HALF_ + i], sv = sinT[t*HALF_ + i];
    float v1 = xn1*cv - xn2*sv;
    float v2 = xn2*cv + xn1*sv;
    size_t o = (size_t)bt * (NB_*C_) + n * C_ + i;
    unsigned short h1 = f2bf(v1), h2 = f2bf(v2);
    Qhi[o]         = h1;
    Qhi[o + HALF_] = h2;
    Qlo[o]         = f2bf(v1 - bf2f(h1));
    Qlo[o + HALF_] = f2bf(v2 - bf2f(h2));
}

// ---------------- RoPE on K rows -> Khi/Klo bf16 ----------------
__global__ __launch_bounds__(256) void k_post2_k(const float* __restrict__ Kf,
                                                 const float* __restrict__ cosT,
                                                 const float* __restrict__ sinT,
                                                 unsigned short* __restrict__ Khi,
                                                 unsigned short* __restrict__ Klo) {
    int bt = blockIdx.x;
    int t  = bt & (T_ - 1);
    const float* row = Kf + (size_t)bt * C_;
    int i = threadIdx.x;
    float x1 = row[i], x2 = row[i + HALF_];
    float cv = cosT[t*HALF_ + i], sv = sinT[t*HALF_ + i];
    float v1 = x1*cv - x2*sv;
    float v2 = x2*cv + x1*sv;
    size_t o = (size_t)bt * C_ + i;
    unsigned short h1 = f2bf(v1), h2 = f2bf(v2);
    Khi[o]         = h1;
    Khi[o + HALF_] = h2;
    Klo[o]         = f2bf(v1 - bf2f(h1));
    Klo[o + HALF_] = f2bf(v2 - bf2f(h2));
}

// ---------------- V transpose + bf16: Vf[bt][nc] -> Vt[(b*2048+nc)][t] ----------------
__global__ __launch_bounds__(256) void vt_k(const float* __restrict__ Vf,
                                            unsigned short* __restrict__ Vt) {
    __shared__ float tileS[64][65];
    int tb  = blockIdx.x & 63;        // bt-tile (64 rows)
    int ncb = blockIdx.x >> 6;        // nc-tile (64 cols), 0..31
    int tid = threadIdx.x;
    int ty = tid >> 6, tx = tid & 63;
    for (int i = ty; i < 64; i += 4)
        tileS[i][tx] = Vf[(size_t)(tb*64 + i) * (NB_*C_) + ncb*64 + tx];
    __syncthreads();
    int bt = tb*64 + tx;
    int b = bt >> 11, t = bt & (T_ - 1);
    for (int j = ty; j < 64; j += 4) {
        int nc = ncb*64 + j;
        Vt[((size_t)(b*(NB_*C_) + nc)) * T_ + t] = f2bf(tileS[tx][j]);
    }
}

// ---------------- fused MFMA attention ----------------
// block = ((b*64 + tt)*NPH2 + phase); 256 thr = 4 waves
// QK rows R = t_local*4 + n (128 rows), cols s (64). wave w owns row-frags {2w,2w+1}.
// PV: wave w owns c-chunk [128w,128w+128), all 4 branches, y in regs.
__global__ __launch_bounds__(256) void attn_mfma_k(
    const unsigned short* __restrict__ Qhi, const unsigned short* __restrict__ Qlo,
    const unsigned short* __restrict__ Khi, const unsigned short* __restrict__ Klo,
    const unsigned short* __restrict__ Vt,
    float* __restrict__ part_y, float* __restrict__ part_S,
    unsigned* __restrict__ part_act)
{
    __shared__ __align__(16) short QhS[128*64];
    __shared__ __align__(16) short QlS[128*64];
    __shared__ __align__(16) short KhS[64*64];
    __shared__ __align__(16) short KlS[64*64];
    __shared__ __align__(16) short Pl[4*32*72];

    int tid = threadIdx.x;
    int w = tid >> 6, l = tid & 63;
    int lhi = l >> 4, llo = l & 15;
    int blk = blockIdx.x;
    int phase = blk & (NPH2 - 1);
    int tt    = (blk >> 2) & 63;
    int b     = blk >> 8;
    int t0 = tt * TT2;
    int tmax = t0 + TT2 - 1;

    f32x4 yacc[2][8];
    #pragma unroll
    for (int i = 0; i < 2; i++)
        #pragma unroll
        for (int j = 0; j < 8; j++) yacc[i][j] = (f32x4){0.f,0.f,0.f,0.f};
    float Sacc[2] = {0.f, 0.f};
    unsigned Aacc[2] = {0u, 0u};

    for (int s0 = phase * ST2; s0 <= tmax; s0 += NPH2 * ST2) {
        f32x4 acc[2][4];
        #pragma unroll
        for (int i = 0; i < 2; i++)
            #pragma unroll
            for (int j = 0; j < 4; j++) acc[i][j] = (f32x4){0.f,0.f,0.f,0.f};

        for (int kc = 0; kc < C_; kc += 64) {
            // ---- stage Q chunk (128 rows x 64 bf16, hi+lo), XOR-swizzled ----
            #pragma unroll
            for (int k2 = 0; k2 < 4; k2++) {
                int g = tid + k2*256;           // granule of 8 bf16
                int R = g >> 3, c8 = g & 7;
                int cs = (c8 ^ (R & 7)) << 3;
                size_t gidx = (size_t)(b*T_ + t0 + (R >> 2)) * (NB_*C_)
                            + (size_t)(R & 3) * C_ + kc + (c8 << 3);
                *(u16x8*)&QhS[R*64 + cs] = *(const u16x8*)(Qhi + gidx);
                *(u16x8*)&QlS[R*64 + cs] = *(const u16x8*)(Qlo + gidx);
            }
            // ---- stage K chunk (64 rows x 64 bf16, hi+lo) ----
            #pragma unroll
            for (int k2 = 0; k2 < 2; k2++) {
                int g = tid + k2*256;
                int Rs = g >> 3, c8 = g & 7;
                int cs = (c8 ^ (Rs & 7)) << 3;
                size_t gidx = (size_t)(b*T_ + s0 + Rs) * C_ + kc + (c8 << 3);
                *(u16x8*)&KhS[Rs*64 + cs] = *(const u16x8*)(Khi + gidx);
                *(u16x8*)&KlS[Rs*64 + cs] = *(const u16x8*)(Klo + gidx);
            }
            __syncthreads();
            #pragma unroll
            for (int ks = 0; ks < 2; ks++) {
                s16x8 bh[4], bl[4];
                #pragma unroll
                for (int cf = 0; cf < 4; cf++) {
                    int srow = cf*16 + llo;
                    int coff = ((ks*4 + lhi) ^ (srow & 7)) << 3;
                    bh[cf] = *(const s16x8*)&KhS[srow*64 + coff];
                    bl[cf] = *(const s16x8*)&KlS[srow*64 + coff];
                }
                #pragma unroll
                for (int rfi = 0; rfi < 2; rfi++) {
                    int R = (2*w + rfi)*16 + llo;
                    int coff = ((ks*4 + lhi) ^ (R & 7)) << 3;
                    s16x8 ah = *(const s16x8*)&QhS[R*64 + coff];
                    s16x8 al = *(const s16x8*)&QlS[R*64 + coff];
                    #pragma unroll
                    for (int cf = 0; cf < 4; cf++) {
                        acc[rfi][cf] = __builtin_amdgcn_mfma_f32_16x16x32_bf16(ah, bh[cf], acc[rfi][cf], 0, 0, 0);
                        acc[rfi][cf] = __builtin_amdgcn_mfma_f32_16x16x32_bf16(ah, bl[cf], acc[rfi][cf], 0, 0, 0);
                        acc[rfi][cf] = __builtin_amdgcn_mfma_f32_16x16x32_bf16(al, bh[cf], acc[rfi][cf], 0, 0, 0);
                    }
                }
            }
            __syncthreads();
        }

        // ---- routing (lane-local across the 4 regs = 4 branches) ----
        #pragma unroll
        for (int rfi = 0; rfi < 2; rfi++) {
            int t_l = (2*w + rfi)*4 + lhi;
            int tg = t0 + t_l;
            #pragma unroll
            for (int cf = 0; cf < 4; cf++) {
                int s_l = cf*16 + llo;
                int sg = s0 + s_l;
                f32x4 v = acc[rfi][cf];
                float wu = 0.f; unsigned bits = 0u;
                if (sg <= tg) {
                    float a0 = v[0]/SQRT_C, a1 = v[1]/SQRT_C, a2 = v[2]/SQRT_C, a3 = v[3]/SQRT_C;
                    float m = fmaxf(fmaxf(a0, a1), fmaxf(a2, a3));
                    float e0 = expf(a0-m), e1 = expf(a1-m), e2 = expf(a2-m), e3 = expf(a3-m);
                    float sum = ((e0 + e1) + e2) + e3;
                    float p0 = e0/sum, p1 = e1/sum, p2 = e2/sum, p3 = e3/sum;
                    float mp = fmaxf(fmaxf(p0, p1), fmaxf(p2, p3));
                    bits = (p0 == mp ? 1u : 0u) | (p1 == mp ? 2u : 0u)
                         | (p2 == mp ? 4u : 0u) | (p3 == mp ? 8u : 0u);
                    wu = fmaxf(m, 0.f) + log1pf(expf(-fabsf(m)));
                    Sacc[rfi] += wu; Aacc[rfi] |= bits;
                }
                unsigned short wub = f2bf(wu);
                Pl[(0*32 + t_l)*72 + s_l] = (bits & 1u) ? (short)wub : (short)0;
                Pl[(1*32 + t_l)*72 + s_l] = (bits & 2u) ? (short)wub : (short)0;
                Pl[(2*32 + t_l)*72 + s_l] = (bits & 4u) ? (short)wub : (short)0;
                Pl[(3*32 + t_l)*72 + s_l] = (bits & 8u) ? (short)wub : (short)0;
            }
        }
        __syncthreads();

        // ---- PV: y[t][c-chunk w] += sum_n P_n @ V_n ----
        #pragma unroll
        for (int ks = 0; ks < 2; ks++) {
            #pragma unroll
            for (int n = 0; n < 4; n++) {
                s16x8 pa[2];
                #pragma unroll
                for (int rp = 0; rp < 2; rp++) {
                    int t_l = rp*16 + llo;
                    pa[rp] = *(const s16x8*)&Pl[(n*32 + t_l)*72 + ks*32 + lhi*8];
                }
                #pragma unroll
                for (int cf = 0; cf < 8; cf++) {
                    int c = 128*w + cf*16 + llo;
                    size_t vidx = ((size_t)(b*(NB_*C_) + n*C_ + c)) * T_ + s0 + ks*32 + lhi*8;
                    s16x8 vb = *(const s16x8*)(Vt + vidx);
                    yacc[0][cf] = __builtin_amdgcn_mfma_f32_16x16x32_bf16(pa[0], vb, yacc[0][cf], 0, 0, 0);
                    yacc[1][cf] = __builtin_amdgcn_mfma_f32_16x16x32_bf16(pa[1], vb, yacc[1][cf], 0, 0, 0);
                }
            }
        }
        __syncthreads();
    }

    // ---- reduce S/act across the 16 s-lanes sharing each t ----
    #pragma unroll
    for (int rfi = 0; rfi < 2; rfi++) {
        float s = Sacc[rfi];
        #pragma unroll
        for (int mask = 1; mask <= 8; mask <<= 1) s += __shfl_xor(s, mask, 64);
        int a = (int)Aacc[rfi];
        #pragma unroll
        for (int mask = 1; mask <= 8; mask <<= 1) a |= __shfl_xor(a, mask, 64);
        if (llo == 0) {
            int t_l = (2*w + rfi)*4 + lhi;
            part_S[(size_t)blk * TT2 + t_l] = s;
            part_act[(size_t)blk * TT2 + t_l] = (unsigned)a;
        }
    }
    // ---- write y partials ----
    #pragma unroll
    for (int rp = 0; rp < 2; rp++)
        #pragma unroll
        for (int cf = 0; cf < 8; cf++)
            #pragma unroll
            for (int r = 0; r < 4; r++) {
                int t_l = rp*16 + lhi*4 + r;
                int c = 128*w + cf*16 + llo;
                part_y[(size_t)blk * (TT2*C_) + (size_t)t_l*C_ + c] = yacc[rp][cf][r];
            }
}

// ---------------- combine phases + sinks -> Y ----------------
__global__ __launch_bounds__(256) void combine2_k(
    const float* __restrict__ part_y, const float* __restrict__ part_S,
    const unsigned* __restrict__ part_act,
    const float* __restrict__ basis, const float* __restrict__ resid_sink,
    float* __restrict__ Y)
{
    int bt = blockIdx.x;
    int t = bt & (T_ - 1);
    int tt = t >> 5, tl = t & 31;
    int b = bt >> 11;
    int i = threadIdx.x;
    int base_blk = (b * 64 + tt) * NPH2;
    float S = 0.f; unsigned act = 0u;
    float y0 = 0.f, y1 = 0.f;
    for (int ph = 0; ph < NPH2; ph++) {
        int pb = base_blk + ph;
        S   += part_S[(size_t)pb * TT2 + tl];
        act |= part_act[(size_t)pb * TT2 + tl];
        y0  += part_y[(size_t)pb * (TT2*C_) + tl*C_ + i];
        y1  += part_y[(size_t)pb * (TT2*C_) + tl*C_ + i + 256];
    }
    float scale = fminf(1.0f / (S + 1e-6f), 1.0f);
    float residual = 1.0f - scale * S;
    if (t < T_ - 1) act = 0xFu;
    float o0 = scale * y0, o1 = scale * y1;
    #pragma unroll
    for (int n = 0; n < 4; n++) if ((act >> n) & 1u) {
        o0 += basis[n*C_ + i];
        o1 += basis[n*C_ + i + 256];
    }
    o0 += residual * resid_sink[i];
    o1 += residual * resid_sink[i + 256];
    Y[(size_t)bt * C_ + i]       = o0;
    Y[(size_t)bt * C_ + i + 256] = o1;
}

extern "C" void kernel_launch(void* const* d_in, const int* in_sizes, int n_in,
                              void* d_out, int out_size, void* d_ws, size_t ws_size,
                              hipStream_t stream) {
    const float* a    = (const float*)d_in[0];
    const float* x    = (const float*)d_in[1];
    const float* Wq   = (const float*)d_in[2];
    const float* Wk   = (const float*)d_in[3];
    const float* Wv   = (const float*)d_in[4];
    const float* Wo   = (const float*)d_in[5];
    const float* vres = (const float*)d_in[6];
    const float* vbas = (const float*)d_in[7];

    float* ws   = (float*)d_ws;
    // float-unit offsets
    float* cosT = ws;                                  // 524288
    float* sinT = cosT + (size_t)T_*HALF_;             // 524288
    float* Qf   = sinT + (size_t)T_*HALF_;             // 8388608 (reused as part_y)
    float* Kf   = Qf + (size_t)BT_*NB_*C_;             // 2097152
    float* Vf   = Kf + (size_t)BT_*C_;                 // 8388608 (reused as Yb/pS/pA)
    unsigned short* Qhi = (unsigned short*)(Vf + (size_t)BT_*NB_*C_);
    unsigned short* Qlo = Qhi + (size_t)BT_*NB_*C_;
    unsigned short* Khi = Qlo + (size_t)BT_*NB_*C_;
    unsigned short* Klo = Khi + (size_t)BT_*C_;
    unsigned short* Vt  = Klo + (size_t)BT_*C_;

    float* part_y = Qf;                                // Qf dead after q_post2
    float* Yb     = Vf;                                // Vf dead after vt_k
    float* pS     = Vf + (size_t)BT_*C_ /*2097152*/;
    unsigned* pA  = (unsigned*)(pS + (size_t)NBLK_ATTN * TT2);

    rope_table_k<<<T_, 256, 0, stream>>>(cosT, sinT);
    sgemm64_k<<<(BT_/64)*((NB_*C_)/64), 256, 0, stream>>>(a, Wq, Qf, BT_, NB_*C_, C_);
    sgemm64_k<<<(BT_/64)*((NB_*C_)/64), 256, 0, stream>>>(a, Wv, Vf, BT_, NB_*C_, C_);
    sgemm64_k<<<(BT_/64)*(C_/64),       256, 0, stream>>>(x, Wk, Kf, BT_, C_, C_);
    q_post2_k<<<BT_*NB_, 256, 0, stream>>>(Qf, cosT, sinT, Qhi, Qlo);
    k_post2_k<<<BT_,     256, 0, stream>>>(Kf, cosT, sinT, Khi, Klo);
    vt_k<<<(BT_/64)*((NB_*C_)/64), 256, 0, stream>>>(Vf, Vt);
    attn_mfma_k<<<NBLK_ATTN, 256, 0, stream>>>(Qhi, Qlo, Khi, Klo, Vt, part_y, pS, pA);
    combine2_k<<<BT_, 256, 0, stream>>>(part_y, pS, pA, vbas, vres, Yb);
    sgemm64_k<<<(BT_/64)*(C_/64), 256, 0, stream>>>(Yb, Wo, (float*)d_out, BT_, C_, C_);
}

// Round 3
// 327.507 us; speedup vs baseline: 7.4033x; 2.3637x over previous
//
#include <hip/hip_runtime.h>
#include <math.h>

#define B_    2
#define T_    2048
#define C_    512
#define NB_   4
#define HALF_ 256
#define BT_   (B_*T_)
#define EPS_  1.1920929e-07f
#define SQRT_C 22.627416997969522f

using f32x4 = __attribute__((ext_vector_type(4))) float;
using s16x8 = __attribute__((ext_vector_type(8))) short;
using u16x8 = __attribute__((ext_vector_type(8))) unsigned short;

__device__ __forceinline__ unsigned short f2bf(float f) {
    unsigned x = __float_as_uint(f);
    unsigned r = (x + 0x7fffu + ((x >> 16) & 1u)) >> 16;
    return (unsigned short)r;
}
__device__ __forceinline__ float bf2f(unsigned short h) {
    return __uint_as_float(((unsigned)h) << 16);
}

// ---------------- RoPE cos/sin tables ----------------
__global__ __launch_bounds__(256) void rope_table_k(float* __restrict__ cosT,
                                                    float* __restrict__ sinT) {
    int t = blockIdx.x;
    int i = threadIdx.x;
    float ex   = (float)i / (float)HALF_;
    float invf = 1.0f / powf(10000.0f, ex);
    float ang  = (float)t * invf;
    float sv, cv;
    sincosf(ang, &sv, &cv);
    cosT[t*HALF_ + i] = cv;
    sinT[t*HALF_ + i] = sv;
}

// ---------------- fp32 -> bf16 hi/lo cast (flat, one float4/thread) ----------------
__global__ __launch_bounds__(256) void cast_hilo_k(const float* __restrict__ src,
                                                   unsigned short* __restrict__ hi,
                                                   unsigned short* __restrict__ lo,
                                                   int n4) {
    int i = blockIdx.x * 256 + threadIdx.x;
    if (i >= n4) return;
    float4 v = ((const float4*)src)[i];
    ushort4 h, l;
    h.x = f2bf(v.x); l.x = f2bf(v.x - bf2f(h.x));
    h.y = f2bf(v.y); l.y = f2bf(v.y - bf2f(h.y));
    h.z = f2bf(v.z); l.z = f2bf(v.z - bf2f(h.z));
    h.w = f2bf(v.w); l.w = f2bf(v.w - bf2f(h.w));
    ((ushort4*)hi)[i] = h;
    ((ushort4*)lo)[i] = l;
}

// ---------------- transpose-cast: W[K][N] fp32 -> Wt[N][K] bf16 (hi, optional lo) ----
__global__ __launch_bounds__(256) void tcast_k(const float* __restrict__ W,
                                               unsigned short* __restrict__ Whi,
                                               unsigned short* __restrict__ Wlo,
                                               int K, int N, int wantLo) {
    __shared__ float tile[64][65];
    int nbt = N >> 6;
    int nb = blockIdx.x % nbt, kb = blockIdx.x / nbt;
    int tid = threadIdx.x;
    int ty = tid >> 6, tx = tid & 63;
    for (int i = ty; i < 64; i += 4)
        tile[i][tx] = W[(size_t)(kb*64 + i) * N + nb*64 + tx];
    __syncthreads();
    for (int j = ty; j < 64; j += 4) {
        float v = tile[tx][j];
        unsigned short h = f2bf(v);
        size_t o = (size_t)(nb*64 + j) * K + kb*64 + tx;
        Whi[o] = h;
        if (wantLo) Wlo[o] = f2bf(v - bf2f(h));
    }
}

// ---------------- generic MFMA GEMM: C[M][N] fp32 = A[M][K] @ Bt[N][K] ----------------
// SPLIT=1: A,B given as hi/lo bf16 pairs, 3-MFMA split product. SPLIT=0: hi only.
// 128x128 tile, BK=64, 4 waves (2x2), XOR-swizzled LDS.
template<int SPLIT>
__global__ __launch_bounds__(256) void mm_k(
    const unsigned short* __restrict__ Ahi, const unsigned short* __restrict__ Alo,
    const unsigned short* __restrict__ Bhi, const unsigned short* __restrict__ Blo,
    float* __restrict__ C, int M, int N, int K)
{
    __shared__ __align__(16) char smem[SPLIT ? 65536 : 32768];
    short* Ah = (short*)smem;
    short* Bh = Ah + 8192;
    short* Al = SPLIT ? (Bh + 8192) : nullptr;
    short* Bl = SPLIT ? (Bh + 16384) : nullptr;

    int tid = threadIdx.x;
    int w = tid >> 6, l = tid & 63;
    int wm = w >> 1, wn = w & 1;
    int llo = l & 15, lhi = l >> 4;
    int nbt = N >> 7;
    int bx = blockIdx.x % nbt, by = blockIdx.x / nbt;
    int m0 = by << 7, n0 = bx << 7;

    f32x4 acc[4][4];
    #pragma unroll
    for (int mi = 0; mi < 4; mi++)
        #pragma unroll
        for (int ni = 0; ni < 4; ni++) acc[mi][ni] = (f32x4){0.f,0.f,0.f,0.f};

    for (int k0 = 0; k0 < K; k0 += 64) {
        #pragma unroll
        for (int i2 = 0; i2 < 4; i2++) {
            int gid = tid + (i2 << 8);
            int r = gid >> 3, gk = gid & 7;
            int ds = r*64 + ((gk ^ (r & 7)) << 3);
            size_t ga = (size_t)(m0 + r) * K + k0 + (gk << 3);
            size_t gb = (size_t)(n0 + r) * K + k0 + (gk << 3);
            *(u16x8*)&Ah[ds] = *(const u16x8*)(Ahi + ga);
            *(u16x8*)&Bh[ds] = *(const u16x8*)(Bhi + gb);
            if constexpr (SPLIT) {
                *(u16x8*)&Al[ds] = *(const u16x8*)(Alo + ga);
                *(u16x8*)&Bl[ds] = *(const u16x8*)(Blo + gb);
            }
        }
        __syncthreads();
        #pragma unroll
        for (int ks = 0; ks < 2; ks++) {
            s16x8 bh[4], bl[4];
            #pragma unroll
            for (int ni = 0; ni < 4; ni++) {
                int br = (wn << 6) + (ni << 4) + llo;
                int bo = br*64 + ((((ks << 2) + lhi) ^ (br & 7)) << 3);
                bh[ni] = *(const s16x8*)&Bh[bo];
                if constexpr (SPLIT) bl[ni] = *(const s16x8*)&Bl[bo];
            }
            #pragma unroll
            for (int mi = 0; mi < 4; mi++) {
                int ar = (wm << 6) + (mi << 4) + llo;
                int ao = ar*64 + ((((ks << 2) + lhi) ^ (ar & 7)) << 3);
                s16x8 ah = *(const s16x8*)&Ah[ao];
                s16x8 al;
                if constexpr (SPLIT) al = *(const s16x8*)&Al[ao];
                #pragma unroll
                for (int ni = 0; ni < 4; ni++) {
                    acc[mi][ni] = __builtin_amdgcn_mfma_f32_16x16x32_bf16(ah, bh[ni], acc[mi][ni], 0, 0, 0);
                    if constexpr (SPLIT) {
                        acc[mi][ni] = __builtin_amdgcn_mfma_f32_16x16x32_bf16(ah, bl[ni], acc[mi][ni], 0, 0, 0);
                        acc[mi][ni] = __builtin_amdgcn_mfma_f32_16x16x32_bf16(al, bh[ni], acc[mi][ni], 0, 0, 0);
                    }
                }
            }
        }
        __syncthreads();
    }
    #pragma unroll
    for (int mi = 0; mi < 4; mi++) {
        int row0 = m0 + (wm << 6) + (mi << 4) + (lhi << 2);
        #pragma unroll
        for (int ni = 0; ni < 4; ni++) {
            int col = n0 + (wn << 6) + (ni << 4) + llo;
            f32x4 v = acc[mi][ni];
            #pragma unroll
            for (int r = 0; r < 4; r++)
                C[(size_t)(row0 + r) * N + col] = v[r];
        }
    }
}

// ---------------- V GEMM (plain bf16) with transposed-bf16 epilogue ----------------
// Vt[(b*2048 + nc)*2048 + t] = bf16( a[bt] @ Wv[:, nc] )
__global__ __launch_bounds__(256) void mm_v_k(
    const unsigned short* __restrict__ Ahi,
    const unsigned short* __restrict__ Bhi,
    unsigned short* __restrict__ Vt, int M, int N, int K)
{
    __shared__ __align__(16) char smem[32768];
    short* Ah = (short*)smem;
    short* Bh = Ah + 8192;
    int tid = threadIdx.x;
    int w = tid >> 6, l = tid & 63;
    int wm = w >> 1, wn = w & 1;
    int llo = l & 15, lhi = l >> 4;
    int nbt = N >> 7;
    int bx = blockIdx.x % nbt, by = blockIdx.x / nbt;
    int m0 = by << 7, n0 = bx << 7;

    f32x4 acc[4][4];
    #pragma unroll
    for (int mi = 0; mi < 4; mi++)
        #pragma unroll
        for (int ni = 0; ni < 4; ni++) acc[mi][ni] = (f32x4){0.f,0.f,0.f,0.f};

    for (int k0 = 0; k0 < K; k0 += 64) {
        #pragma unroll
        for (int i2 = 0; i2 < 4; i2++) {
            int gid = tid + (i2 << 8);
            int r = gid >> 3, gk = gid & 7;
            int ds = r*64 + ((gk ^ (r & 7)) << 3);
            *(u16x8*)&Ah[ds] = *(const u16x8*)(Ahi + (size_t)(m0 + r) * K + k0 + (gk << 3));
            *(u16x8*)&Bh[ds] = *(const u16x8*)(Bhi + (size_t)(n0 + r) * K + k0 + (gk << 3));
        }
        __syncthreads();
        #pragma unroll
        for (int ks = 0; ks < 2; ks++) {
            s16x8 bh[4];
            #pragma unroll
            for (int ni = 0; ni < 4; ni++) {
                int br = (wn << 6) + (ni << 4) + llo;
                bh[ni] = *(const s16x8*)&Bh[br*64 + ((((ks << 2) + lhi) ^ (br & 7)) << 3)];
            }
            #pragma unroll
            for (int mi = 0; mi < 4; mi++) {
                int ar = (wm << 6) + (mi << 4) + llo;
                s16x8 ah = *(const s16x8*)&Ah[ar*64 + ((((ks << 2) + lhi) ^ (ar & 7)) << 3)];
                #pragma unroll
                for (int ni = 0; ni < 4; ni++)
                    acc[mi][ni] = __builtin_amdgcn_mfma_f32_16x16x32_bf16(ah, bh[ni], acc[mi][ni], 0, 0, 0);
            }
        }
        __syncthreads();
    }
    #pragma unroll
    for (int mi = 0; mi < 4; mi++) {
        int row0 = m0 + (wm << 6) + (mi << 4) + (lhi << 2);  // bt, 4 consecutive
        int b = row0 >> 11, t = row0 & (T_ - 1);
        #pragma unroll
        for (int ni = 0; ni < 4; ni++) {
            int col = n0 + (wn << 6) + (ni << 4) + llo;       // nc
            f32x4 v = acc[mi][ni];
            ushort4 o;
            o.x = f2bf(v[0]); o.y = f2bf(v[1]); o.z = f2bf(v[2]); o.w = f2bf(v[3]);
            *(ushort4*)(Vt + ((size_t)(b*(NB_*C_) + col)) * T_ + t) = o;
        }
    }
}

// ---------------- RMSNorm + RoPE on Q rows -> Qhi/Qlo bf16 ----------------
__global__ __launch_bounds__(256) void q_post2_k(const float* __restrict__ Qf,
                                                 const float* __restrict__ cosT,
                                                 const float* __restrict__ sinT,
                                                 unsigned short* __restrict__ Qhi,
                                                 unsigned short* __restrict__ Qlo) {
    int blk = blockIdx.x;
    int n  = blk & 3;
    int bt = blk >> 2;
    int t  = bt & (T_ - 1);
    const float* row = Qf + (size_t)bt * (NB_*C_) + n * C_;
    int i = threadIdx.x;
    float x1 = row[i], x2 = row[i + HALF_];
    __shared__ float red[256];
    red[i] = x1*x1 + x2*x2;
    __syncthreads();
    for (int s = 128; s > 0; s >>= 1) {
        if (i < s) red[i] += red[i + s];
        __syncthreads();
    }
    float mean = red[0] * (1.0f / (float)C_);
    float r = rsqrtf(mean + EPS_);
    float xn1 = x1 * r, xn2 = x2 * r;
    float cv = cosT[t*HALF_ + i], sv = sinT[t*HALF_ + i];
    float v1 = xn1*cv - xn2*sv;
    float v2 = xn2*cv + xn1*sv;
    size_t o = (size_t)bt * (NB_*C_) + n * C_ + i;
    unsigned short h1 = f2bf(v1), h2 = f2bf(v2);
    Qhi[o]         = h1;
    Qhi[o + HALF_] = h2;
    Qlo[o]         = f2bf(v1 - bf2f(h1));
    Qlo[o + HALF_] = f2bf(v2 - bf2f(h2));
}

// ---------------- RoPE on K rows -> Khi/Klo bf16 ----------------
__global__ __launch_bounds__(256) void k_post2_k(const float* __restrict__ Kf,
                                                 const float* __restrict__ cosT,
                                                 const float* __restrict__ sinT,
                                                 unsigned short* __restrict__ Khi,
                                                 unsigned short* __restrict__ Klo) {
    int bt = blockIdx.x;
    int t  = bt & (T_ - 1);
    const float* row = Kf + (size_t)bt * C_;
    int i = threadIdx.x;
    float x1 = row[i], x2 = row[i + HALF_];
    float cv = cosT[t*HALF_ + i], sv = sinT[t*HALF_ + i];
    float v1 = x1*cv - x2*sv;
    float v2 = x2*cv + x1*sv;
    size_t o = (size_t)bt * C_ + i;
    unsigned short h1 = f2bf(v1), h2 = f2bf(v2);
    Khi[o]         = h1;
    Khi[o + HALF_] = h2;
    Klo[o]         = f2bf(v1 - bf2f(h1));
    Klo[o + HALF_] = f2bf(v2 - bf2f(h2));
}

// ---------------- QK + routing pass ----------------
// grid dense (b, tt:64, st:16); active iff st*128 <= tt*32+31.
// A rows R = t_local*4 + n (128), B rows = s (128), K = 512, split-bf16 3-MFMA.
// Outputs: P[b][n][t][s] bf16; partS/partA[((b*64+tt)*16+st)*2+wn][32].
__global__ __launch_bounds__(256) void qk_routing_k(
    const unsigned short* __restrict__ Qhi, const unsigned short* __restrict__ Qlo,
    const unsigned short* __restrict__ Khi, const unsigned short* __restrict__ Klo,
    unsigned short* __restrict__ P, float* __restrict__ partS, unsigned* __restrict__ partA)
{
    __shared__ __align__(16) char smem[65536];
    short* Ah = (short*)smem;
    short* Bh = Ah + 8192;
    short* Al = Bh + 8192;
    short* Bl = Bh + 16384;

    int tid = threadIdx.x;
    int w = tid >> 6, l = tid & 63;
    int wm = w >> 1, wn = w & 1;
    int llo = l & 15, lhi = l >> 4;
    int bid = blockIdx.x;
    int st = bid & 15, tt = (bid >> 4) & 63, b = bid >> 10;
    int t0 = tt << 5, s0 = st << 7;
    if (s0 > t0 + 31) return;

    f32x4 acc[4][4];
    #pragma unroll
    for (int mi = 0; mi < 4; mi++)
        #pragma unroll
        for (int ni = 0; ni < 4; ni++) acc[mi][ni] = (f32x4){0.f,0.f,0.f,0.f};

    for (int k0 = 0; k0 < C_; k0 += 64) {
        #pragma unroll
        for (int i2 = 0; i2 < 4; i2++) {
            int gid = tid + (i2 << 8);
            int r = gid >> 3, gk = gid & 7;
            int ds = r*64 + ((gk ^ (r & 7)) << 3);
            size_t ga = (size_t)(b*T_ + t0 + (r >> 2)) * (NB_*C_) + ((r & 3) << 9) + k0 + (gk << 3);
            size_t gb = (size_t)(b*T_ + s0 + r) * C_ + k0 + (gk << 3);
            *(u16x8*)&Ah[ds] = *(const u16x8*)(Qhi + ga);
            *(u16x8*)&Al[ds] = *(const u16x8*)(Qlo + ga);
            *(u16x8*)&Bh[ds] = *(const u16x8*)(Khi + gb);
            *(u16x8*)&Bl[ds] = *(const u16x8*)(Klo + gb);
        }
        __syncthreads();
        #pragma unroll
        for (int ks = 0; ks < 2; ks++) {
            s16x8 bh[4], bl[4];
            #pragma unroll
            for (int ni = 0; ni < 4; ni++) {
                int br = (wn << 6) + (ni << 4) + llo;
                int bo = br*64 + ((((ks << 2) + lhi) ^ (br & 7)) << 3);
                bh[ni] = *(const s16x8*)&Bh[bo];
                bl[ni] = *(const s16x8*)&Bl[bo];
            }
            #pragma unroll
            for (int mi = 0; mi < 4; mi++) {
                int ar = (wm << 6) + (mi << 4) + llo;
                int ao = ar*64 + ((((ks << 2) + lhi) ^ (ar & 7)) << 3);
                s16x8 ah = *(const s16x8*)&Ah[ao];
                s16x8 al = *(const s16x8*)&Al[ao];
                #pragma unroll
                for (int ni = 0; ni < 4; ni++) {
                    acc[mi][ni] = __builtin_amdgcn_mfma_f32_16x16x32_bf16(ah, bh[ni], acc[mi][ni], 0, 0, 0);
                    acc[mi][ni] = __builtin_amdgcn_mfma_f32_16x16x32_bf16(ah, bl[ni], acc[mi][ni], 0, 0, 0);
                    acc[mi][ni] = __builtin_amdgcn_mfma_f32_16x16x32_bf16(al, bh[ni], acc[mi][ni], 0, 0, 0);
                }
            }
        }
        __syncthreads();
    }

    // ---- routing epilogue; P staged in LDS [4][32][136] (reuses smem) ----
    short* Pl = (short*)smem;
    #pragma unroll
    for (int mi = 0; mi < 4; mi++) {
        int tl = (wm << 4) + (mi << 2) + lhi;
        int tg = t0 + tl;
        float wsum = 0.f; unsigned ab = 0u;
        #pragma unroll
        for (int ni = 0; ni < 4; ni++) {
            int sl = (wn << 6) + (ni << 4) + llo;
            int sg = s0 + sl;
            f32x4 v = acc[mi][ni];
            float wu = 0.f; unsigned bits = 0u;
            if (sg <= tg) {
                float a0 = v[0]/SQRT_C, a1 = v[1]/SQRT_C, a2 = v[2]/SQRT_C, a3 = v[3]/SQRT_C;
                float m = fmaxf(fmaxf(a0, a1), fmaxf(a2, a3));
                float e0 = expf(a0-m), e1 = expf(a1-m), e2 = expf(a2-m), e3 = expf(a3-m);
                float sum = ((e0 + e1) + e2) + e3;
                float p0 = e0/sum, p1 = e1/sum, p2 = e2/sum, p3 = e3/sum;
                float mp = fmaxf(fmaxf(p0, p1), fmaxf(p2, p3));
                bits = (p0 == mp ? 1u : 0u) | (p1 == mp ? 2u : 0u)
                     | (p2 == mp ? 4u : 0u) | (p3 == mp ? 8u : 0u);
                wu = fmaxf(m, 0.f) + log1pf(expf(-fabsf(m)));
                wsum += wu; ab |= bits;
            }
            unsigned short wub = f2bf(wu);
            Pl[(0*32 + tl)*136 + sl] = (bits & 1u) ? (short)wub : (short)0;
            Pl[(1*32 + tl)*136 + sl] = (bits & 2u) ? (short)wub : (short)0;
            Pl[(2*32 + tl)*136 + sl] = (bits & 4u) ? (short)wub : (short)0;
            Pl[(3*32 + tl)*136 + sl] = (bits & 8u) ? (short)wub : (short)0;
        }
        #pragma unroll
        for (int mask = 1; mask <= 8; mask <<= 1) wsum += __shfl_xor(wsum, mask, 64);
        int ai = (int)ab;
        #pragma unroll
        for (int mask = 1; mask <= 8; mask <<= 1) ai |= __shfl_xor(ai, mask, 64);
        if (llo == 0) {
            size_t pidx = ((((size_t)(b*64 + tt) * 16 + st) * 2 + wn) * 32) + tl;
            partS[pidx] = wsum;
            partA[pidx] = (unsigned)ai;
        }
    }
    __syncthreads();
    // ---- copy P tile to global (coalesced 16B) ----
    for (int i = tid; i < 2048; i += 256) {
        int row = i >> 4, g8 = i & 15;
        int n = row >> 5, tl = row & 31;
        u16x8 v = *(const u16x8*)&Pl[row*136 + (g8 << 3)];
        *(u16x8*)(P + ((size_t)((b*4 + n)*T_ + t0 + tl)) * T_ + s0 + (g8 << 3)) = v;
    }
}

// ---------------- PV pass: y[b][t][c] = sum_n P_n @ V_n, 4-phase k-split ----------------
// grid (b:2, tt:16, cc:4, ph:4) = 512 blocks. py[ph] partial buffers.
__global__ __launch_bounds__(256) void pv_k(
    const unsigned short* __restrict__ P, const unsigned short* __restrict__ Vt,
    float* __restrict__ py)
{
    __shared__ __align__(16) char smem[32768];
    short* Ah = (short*)smem;
    short* Bh = Ah + 8192;
    int tid = threadIdx.x;
    int w = tid >> 6, l = tid & 63;
    int wm = w >> 1, wn = w & 1;
    int llo = l & 15, lhi = l >> 4;
    int bid = blockIdx.x;
    int ph = bid & 3, cc = (bid >> 2) & 3, tt = (bid >> 4) & 15, b = bid >> 8;
    int t0 = tt << 7, c0 = cc << 7;

    f32x4 acc[4][4];
    #pragma unroll
    for (int mi = 0; mi < 4; mi++)
        #pragma unroll
        for (int ni = 0; ni < 4; ni++) acc[mi][ni] = (f32x4){0.f,0.f,0.f,0.f};

    for (int n = 0; n < 4; n++) {
        for (int sb = ph * 128; sb <= t0 + 127; sb += 512) {
            #pragma unroll
            for (int h = 0; h < 2; h++) {
                int k0 = sb + h*64;
                #pragma unroll
                for (int i2 = 0; i2 < 4; i2++) {
                    int gid = tid + (i2 << 8);
                    int r = gid >> 3, gk = gid & 7;
                    int ds = r*64 + ((gk ^ (r & 7)) << 3);
                    *(u16x8*)&Ah[ds] = *(const u16x8*)(P + ((size_t)((b*4 + n)*T_ + t0 + r)) * T_ + k0 + (gk << 3));
                    *(u16x8*)&Bh[ds] = *(const u16x8*)(Vt + ((size_t)(b*(NB_*C_) + (n << 9) + c0 + r)) * T_ + k0 + (gk << 3));
                }
                __syncthreads();
                #pragma unroll
                for (int ks = 0; ks < 2; ks++) {
                    s16x8 bh[4];
                    #pragma unroll
                    for (int ni = 0; ni < 4; ni++) {
                        int br = (wn << 6) + (ni << 4) + llo;
                        bh[ni] = *(const s16x8*)&Bh[br*64 + ((((ks << 2) + lhi) ^ (br & 7)) << 3)];
                    }
                    #pragma unroll
                    for (int mi = 0; mi < 4; mi++) {
                        int ar = (wm << 6) + (mi << 4) + llo;
                        s16x8 ah = *(const s16x8*)&Ah[ar*64 + ((((ks << 2) + lhi) ^ (ar & 7)) << 3)];
                        #pragma unroll
                        for (int ni = 0; ni < 4; ni++)
                            acc[mi][ni] = __builtin_amdgcn_mfma_f32_16x16x32_bf16(ah, bh[ni], acc[mi][ni], 0, 0, 0);
                    }
                }
                __syncthreads();
            }
        }
    }
    float* out = py + (size_t)ph * (BT_*(size_t)C_);
    #pragma unroll
    for (int mi = 0; mi < 4; mi++) {
        int row0 = t0 + (wm << 6) + (mi << 4) + (lhi << 2);
        #pragma unroll
        for (int ni = 0; ni < 4; ni++) {
            int col = c0 + (wn << 6) + (ni << 4) + llo;
            f32x4 v = acc[mi][ni];
            #pragma unroll
            for (int r = 0; r < 4; r++)
                out[(size_t)(b*T_ + row0 + r) * C_ + col] = v[r];
        }
    }
}

// ---------------- combine: y partials + S/act + sinks -> ybf16 ----------------
__global__ __launch_bounds__(256) void combine3_k(
    const float* __restrict__ py, const float* __restrict__ partS,
    const unsigned* __restrict__ partA,
    const float* __restrict__ basis, const float* __restrict__ resid_sink,
    unsigned short* __restrict__ ybf)
{
    int bt = blockIdx.x;
    int t = bt & (T_ - 1);
    int b = bt >> 11;
    int i = threadIdx.x;
    int tt32 = t >> 5, tl = t & 31;
    int stmax = tt32 >> 2;
    float S = 0.f; unsigned act = 0u;
    for (int st = 0; st <= stmax; st++) {
        #pragma unroll
        for (int wn = 0; wn < 2; wn++) {
            size_t idx = ((((size_t)(b*64 + tt32) * 16 + st) * 2 + wn) * 32) + tl;
            S += partS[idx];
            act |= partA[idx];
        }
    }
    float y0 = 0.f, y1 = 0.f;
    #pragma unroll
    for (int ph = 0; ph < 4; ph++) {
        y0 += py[(size_t)ph * (BT_*(size_t)C_) + (size_t)bt * C_ + i];
        y1 += py[(size_t)ph * (BT_*(size_t)C_) + (size_t)bt * C_ + i + 256];
    }
    float scale = fminf(1.0f / (S + 1e-6f), 1.0f);
    float residual = 1.0f - scale * S;
    if (t < T_ - 1) act = 0xFu;
    float o0 = scale * y0, o1 = scale * y1;
    #pragma unroll
    for (int n = 0; n < 4; n++) if ((act >> n) & 1u) {
        o0 += basis[n*C_ + i];
        o1 += basis[n*C_ + i + 256];
    }
    o0 += residual * resid_sink[i];
    o1 += residual * resid_sink[i + 256];
    ybf[(size_t)bt * C_ + i]       = f2bf(o0);
    ybf[(size_t)bt * C_ + i + 256] = f2bf(o1);
}

extern "C" void kernel_launch(void* const* d_in, const int* in_sizes, int n_in,
                              void* d_out, int out_size, void* d_ws, size_t ws_size,
                              hipStream_t stream) {
    const float* a    = (const float*)d_in[0];
    const float* x    = (const float*)d_in[1];
    const float* Wq   = (const float*)d_in[2];
    const float* Wk   = (const float*)d_in[3];
    const float* Wv   = (const float*)d_in[4];
    const float* Wo   = (const float*)d_in[5];
    const float* vres = (const float*)d_in[6];
    const float* vbas = (const float*)d_in[7];

    float* ws = (float*)d_ws;
    float* cosT = ws;                              // 524288 f
    float* sinT = cosT + 524288;                   // 524288 f
    float* Qf   = sinT + 524288;                   // 8388608 f (reused as py)
    float* Kf   = Qf + 8388608;                    // 2097152 f (reused: partS/partA/ybf)
    unsigned short* ahi  = (unsigned short*)(Kf + 2097152);
    unsigned short* alo  = ahi  + 2097152;
    unsigned short* xhi  = alo  + 2097152;
    unsigned short* xlo  = xhi  + 2097152;
    unsigned short* Wqth = xlo  + 2097152;
    unsigned short* Wqtl = Wqth + 1048576;
    unsigned short* Wkth = Wqtl + 1048576;
    unsigned short* Wktl = Wkth + 262144;
    unsigned short* Wvth = Wktl + 262144;
    unsigned short* Woth = Wvth + 1048576;
    unsigned short* Qhi  = Woth + 262144;
    unsigned short* Qlo  = Qhi  + 8388608;
    unsigned short* Khi  = Qlo  + 8388608;
    unsigned short* Klo  = Khi  + 2097152;
    unsigned short* Vt   = Klo  + 2097152;
    unsigned short* P    = Vt   + 8388608;         // 33554432 shorts

    float* py = Qf;
    float* partS = Kf;
    unsigned* partA = (unsigned*)(Kf + 131072);
    unsigned short* ybf = (unsigned short*)(Kf + 262144);

    rope_table_k<<<T_, 256, 0, stream>>>(cosT, sinT);
    cast_hilo_k<<<2048, 256, 0, stream>>>(a, ahi, alo, 524288);
    cast_hilo_k<<<2048, 256, 0, stream>>>(x, xhi, xlo, 524288);
    tcast_k<<<256, 256, 0, stream>>>(Wq, Wqth, Wqtl, 512, 2048, 1);
    tcast_k<<<64,  256, 0, stream>>>(Wk, Wkth, Wktl, 512, 512,  1);
    tcast_k<<<256, 256, 0, stream>>>(Wv, Wvth, nullptr, 512, 2048, 0);
    tcast_k<<<64,  256, 0, stream>>>(Wo, Woth, nullptr, 512, 512,  0);

    mm_k<1><<<512, 256, 0, stream>>>(ahi, alo, Wqth, Wqtl, Qf, BT_, 2048, 512);
    mm_k<1><<<128, 256, 0, stream>>>(xhi, xlo, Wkth, Wktl, Kf, BT_, 512, 512);
    mm_v_k<<<512, 256, 0, stream>>>(ahi, Wvth, Vt, BT_, 2048, 512);

    q_post2_k<<<BT_*NB_, 256, 0, stream>>>(Qf, cosT, sinT, Qhi, Qlo);
    k_post2_k<<<BT_,     256, 0, stream>>>(Kf, cosT, sinT, Khi, Klo);

    qk_routing_k<<<2048, 256, 0, stream>>>(Qhi, Qlo, Khi, Klo, P, partS, partA);
    pv_k<<<512, 256, 0, stream>>>(P, Vt, py);
    combine3_k<<<BT_, 256, 0, stream>>>(py, partS, partA, vbas, vres, ybf);

    mm_k<0><<<128, 256, 0, stream>>>(ybf, nullptr, Woth, nullptr, (float*)d_out, BT_, 512, 512);
}

// Round 4
// 310.604 us; speedup vs baseline: 7.8062x; 1.0544x over previous
//
#include <hip/hip_runtime.h>
#include <math.h>

#define B_    2
#define T_    2048
#define C_    512
#define NB_   4
#define HALF_ 256
#define BT_   (B_*T_)
#define EPS_  1.1920929e-07f
#define SQRT_C 22.627416997969522f

using f32x4 = __attribute__((ext_vector_type(4))) float;
using s16x8 = __attribute__((ext_vector_type(8))) short;
using u16x8 = __attribute__((ext_vector_type(8))) unsigned short;

__device__ __forceinline__ unsigned short f2bf(float f) {
    unsigned x = __float_as_uint(f);
    unsigned r = (x + 0x7fffu + ((x >> 16) & 1u)) >> 16;
    return (unsigned short)r;
}
__device__ __forceinline__ float bf2f(unsigned short h) {
    return __uint_as_float(((unsigned)h) << 16);
}

// direct global->LDS 16B copy: per-lane global src, wave-uniform LDS base (+lane*16 in HW)
__device__ __forceinline__ void gl16(const void* g, void* l) {
    __builtin_amdgcn_global_load_lds(
        (const __attribute__((address_space(1))) unsigned int*)g,
        (__attribute__((address_space(3))) unsigned int*)l, 16, 0, 0);
}

// ---------------- RoPE cos/sin tables ----------------
__global__ __launch_bounds__(256) void rope_table_k(float* __restrict__ cosT,
                                                    float* __restrict__ sinT) {
    int t = blockIdx.x;
    int i = threadIdx.x;
    float ex   = (float)i / (float)HALF_;
    float invf = 1.0f / powf(10000.0f, ex);
    float ang  = (float)t * invf;
    float sv, cv;
    sincosf(ang, &sv, &cv);
    cosT[t*HALF_ + i] = cv;
    sinT[t*HALF_ + i] = sv;
}

// ---------------- fp32 -> bf16 hi/lo cast for a and x in one launch ----------------
__global__ __launch_bounds__(256) void cast2_hilo_k(const float* __restrict__ a,
                                                    const float* __restrict__ x,
                                                    unsigned short* __restrict__ ahi,
                                                    unsigned short* __restrict__ alo,
                                                    unsigned short* __restrict__ xhi,
                                                    unsigned short* __restrict__ xlo) {
    int i = blockIdx.x * 256 + threadIdx.x;
    const float* src; unsigned short *hi, *lo;
    if (i < 524288) { src = a; hi = ahi; lo = alo; }
    else { i -= 524288; src = x; hi = xhi; lo = xlo; }
    float4 v = ((const float4*)src)[i];
    ushort4 h, l;
    h.x = f2bf(v.x); l.x = f2bf(v.x - bf2f(h.x));
    h.y = f2bf(v.y); l.y = f2bf(v.y - bf2f(h.y));
    h.z = f2bf(v.z); l.z = f2bf(v.z - bf2f(h.z));
    h.w = f2bf(v.w); l.w = f2bf(v.w - bf2f(h.w));
    ((ushort4*)hi)[i] = h;
    ((ushort4*)lo)[i] = l;
}

// ---------------- transpose-cast: W[K][N] fp32 -> Wt[N][K] bf16 (hi, optional lo) ----
__global__ __launch_bounds__(256) void tcast_k(const float* __restrict__ W,
                                               unsigned short* __restrict__ Whi,
                                               unsigned short* __restrict__ Wlo,
                                               int K, int N, int wantLo) {
    __shared__ float tile[64][65];
    int nbt = N >> 6;
    int nb = blockIdx.x % nbt, kb = blockIdx.x / nbt;
    int tid = threadIdx.x;
    int ty = tid >> 6, tx = tid & 63;
    for (int i = ty; i < 64; i += 4)
        tile[i][tx] = W[(size_t)(kb*64 + i) * N + nb*64 + tx];
    __syncthreads();
    for (int j = ty; j < 64; j += 4) {
        float v = tile[tx][j];
        unsigned short h = f2bf(v);
        size_t o = (size_t)(nb*64 + j) * K + kb*64 + tx;
        Whi[o] = h;
        if (wantLo) Wlo[o] = f2bf(v - bf2f(h));
    }
}

// ---------------- generic MFMA GEMM: C[M][N] fp32 = A[M][K] @ Bt[N][K] ----------------
// 128x128 tile, BK=64, 4 waves (2x2). global_load_lds staging: linear LDS dest,
// pre-swizzled global src; swizzled ds_read_b128 consume.
template<int SPLIT>
__global__ __launch_bounds__(256) void mm_k(
    const unsigned short* __restrict__ Ahi, const unsigned short* __restrict__ Alo,
    const unsigned short* __restrict__ Bhi, const unsigned short* __restrict__ Blo,
    float* __restrict__ C, int M, int N, int K)
{
    __shared__ __align__(16) char smem[SPLIT ? 65536 : 32768];
    short* Ah = (short*)smem;
    short* Bh = Ah + 8192;
    short* Al = SPLIT ? (Bh + 8192) : nullptr;
    short* Bl = SPLIT ? (Bh + 16384) : nullptr;

    int tid = threadIdx.x;
    int w = tid >> 6, l = tid & 63;
    int wm = w >> 1, wn = w & 1;
    int llo = l & 15, lhi = l >> 4;
    int rl = l >> 3, gs = l & 7;      // staging lane roles: row-in-8, granule slot
    int rb = w << 5;                  // wave's 32-row staging segment
    int nbt = N >> 7;
    int bx = blockIdx.x % nbt, by = blockIdx.x / nbt;
    int m0 = by << 7, n0 = bx << 7;

    f32x4 acc[4][4];
    #pragma unroll
    for (int mi = 0; mi < 4; mi++)
        #pragma unroll
        for (int ni = 0; ni < 4; ni++) acc[mi][ni] = (f32x4){0.f,0.f,0.f,0.f};

    for (int k0 = 0; k0 < K; k0 += 64) {
        #pragma unroll
        for (int i8 = 0; i8 < 4; i8++) {
            int r = rb + (i8 << 3) + rl;
            int sg = (gs ^ (r & 7)) << 3;
            int dsb = (rb + (i8 << 3)) * 64;
            gl16(Ahi + (size_t)(m0 + r) * K + k0 + sg, Ah + dsb);
            gl16(Bhi + (size_t)(n0 + r) * K + k0 + sg, Bh + dsb);
            if constexpr (SPLIT) {
                gl16(Alo + (size_t)(m0 + r) * K + k0 + sg, Al + dsb);
                gl16(Blo + (size_t)(n0 + r) * K + k0 + sg, Bl + dsb);
            }
        }
        __syncthreads();
        #pragma unroll
        for (int ks = 0; ks < 2; ks++) {
            s16x8 bh[4], bl[4];
            #pragma unroll
            for (int ni = 0; ni < 4; ni++) {
                int br = (wn << 6) + (ni << 4) + llo;
                int bo = br*64 + ((((ks << 2) + lhi) ^ (br & 7)) << 3);
                bh[ni] = *(const s16x8*)&Bh[bo];
                if constexpr (SPLIT) bl[ni] = *(const s16x8*)&Bl[bo];
            }
            #pragma unroll
            for (int mi = 0; mi < 4; mi++) {
                int ar = (wm << 6) + (mi << 4) + llo;
                int ao = ar*64 + ((((ks << 2) + lhi) ^ (ar & 7)) << 3);
                s16x8 ah = *(const s16x8*)&Ah[ao];
                s16x8 al;
                if constexpr (SPLIT) al = *(const s16x8*)&Al[ao];
                #pragma unroll
                for (int ni = 0; ni < 4; ni++) {
                    acc[mi][ni] = __builtin_amdgcn_mfma_f32_16x16x32_bf16(ah, bh[ni], acc[mi][ni], 0, 0, 0);
                    if constexpr (SPLIT) {
                        acc[mi][ni] = __builtin_amdgcn_mfma_f32_16x16x32_bf16(ah, bl[ni], acc[mi][ni], 0, 0, 0);
                        acc[mi][ni] = __builtin_amdgcn_mfma_f32_16x16x32_bf16(al, bh[ni], acc[mi][ni], 0, 0, 0);
                    }
                }
            }
        }
        __syncthreads();
    }
    #pragma unroll
    for (int mi = 0; mi < 4; mi++) {
        int row0 = m0 + (wm << 6) + (mi << 4) + (lhi << 2);
        #pragma unroll
        for (int ni = 0; ni < 4; ni++) {
            int col = n0 + (wn << 6) + (ni << 4) + llo;
            f32x4 v = acc[mi][ni];
            #pragma unroll
            for (int r = 0; r < 4; r++)
                C[(size_t)(row0 + r) * N + col] = v[r];
        }
    }
}

// ---------------- V GEMM (plain bf16) with transposed-bf16 epilogue ----------------
__global__ __launch_bounds__(256) void mm_v_k(
    const unsigned short* __restrict__ Ahi,
    const unsigned short* __restrict__ Bhi,
    unsigned short* __restrict__ Vt, int M, int N, int K)
{
    __shared__ __align__(16) char smem[32768];
    short* Ah = (short*)smem;
    short* Bh = Ah + 8192;
    int tid = threadIdx.x;
    int w = tid >> 6, l = tid & 63;
    int wm = w >> 1, wn = w & 1;
    int llo = l & 15, lhi = l >> 4;
    int rl = l >> 3, gs = l & 7;
    int rb = w << 5;
    int nbt = N >> 7;
    int bx = blockIdx.x % nbt, by = blockIdx.x / nbt;
    int m0 = by << 7, n0 = bx << 7;

    f32x4 acc[4][4];
    #pragma unroll
    for (int mi = 0; mi < 4; mi++)
        #pragma unroll
        for (int ni = 0; ni < 4; ni++) acc[mi][ni] = (f32x4){0.f,0.f,0.f,0.f};

    for (int k0 = 0; k0 < K; k0 += 64) {
        #pragma unroll
        for (int i8 = 0; i8 < 4; i8++) {
            int r = rb + (i8 << 3) + rl;
            int sg = (gs ^ (r & 7)) << 3;
            int dsb = (rb + (i8 << 3)) * 64;
            gl16(Ahi + (size_t)(m0 + r) * K + k0 + sg, Ah + dsb);
            gl16(Bhi + (size_t)(n0 + r) * K + k0 + sg, Bh + dsb);
        }
        __syncthreads();
        #pragma unroll
        for (int ks = 0; ks < 2; ks++) {
            s16x8 bh[4];
            #pragma unroll
            for (int ni = 0; ni < 4; ni++) {
                int br = (wn << 6) + (ni << 4) + llo;
                bh[ni] = *(const s16x8*)&Bh[br*64 + ((((ks << 2) + lhi) ^ (br & 7)) << 3)];
            }
            #pragma unroll
            for (int mi = 0; mi < 4; mi++) {
                int ar = (wm << 6) + (mi << 4) + llo;
                s16x8 ah = *(const s16x8*)&Ah[ar*64 + ((((ks << 2) + lhi) ^ (ar & 7)) << 3)];
                #pragma unroll
                for (int ni = 0; ni < 4; ni++)
                    acc[mi][ni] = __builtin_amdgcn_mfma_f32_16x16x32_bf16(ah, bh[ni], acc[mi][ni], 0, 0, 0);
            }
        }
        __syncthreads();
    }
    #pragma unroll
    for (int mi = 0; mi < 4; mi++) {
        int row0 = m0 + (wm << 6) + (mi << 4) + (lhi << 2);
        int b = row0 >> 11, t = row0 & (T_ - 1);
        #pragma unroll
        for (int ni = 0; ni < 4; ni++) {
            int col = n0 + (wn << 6) + (ni << 4) + llo;
            f32x4 v = acc[mi][ni];
            ushort4 o;
            o.x = f2bf(v[0]); o.y = f2bf(v[1]); o.z = f2bf(v[2]); o.w = f2bf(v[3]);
            *(ushort4*)(Vt + ((size_t)(b*(NB_*C_) + col)) * T_ + t) = o;
        }
    }
}

// ---------------- RMSNorm + RoPE on Q rows -> Qhi/Qlo bf16 ----------------
__global__ __launch_bounds__(256) void q_post2_k(const float* __restrict__ Qf,
                                                 const float* __restrict__ cosT,
                                                 const float* __restrict__ sinT,
                                                 unsigned short* __restrict__ Qhi,
                                                 unsigned short* __restrict__ Qlo) {
    int blk = blockIdx.x;
    int n  = blk & 3;
    int bt = blk >> 2;
    int t  = bt & (T_ - 1);
    const float* row = Qf + (size_t)bt * (NB_*C_) + n * C_;
    int i = threadIdx.x;
    float x1 = row[i], x2 = row[i + HALF_];
    __shared__ float red[256];
    red[i] = x1*x1 + x2*x2;
    __syncthreads();
    for (int s = 128; s > 0; s >>= 1) {
        if (i < s) red[i] += red[i + s];
        __syncthreads();
    }
    float mean = red[0] * (1.0f / (float)C_);
    float r = rsqrtf(mean + EPS_);
    float xn1 = x1 * r, xn2 = x2 * r;
    float cv = cosT[t*HALF_ + i], sv = sinT[t*HALF_ + i];
    float v1 = xn1*cv - xn2*sv;
    float v2 = xn2*cv + xn1*sv;
    size_t o = (size_t)bt * (NB_*C_) + n * C_ + i;
    unsigned short h1 = f2bf(v1), h2 = f2bf(v2);
    Qhi[o]         = h1;
    Qhi[o + HALF_] = h2;
    Qlo[o]         = f2bf(v1 - bf2f(h1));
    Qlo[o + HALF_] = f2bf(v2 - bf2f(h2));
}

// ---------------- RoPE on K rows -> Khi/Klo bf16 ----------------
__global__ __launch_bounds__(256) void k_post2_k(const float* __restrict__ Kf,
                                                 const float* __restrict__ cosT,
                                                 const float* __restrict__ sinT,
                                                 unsigned short* __restrict__ Khi,
                                                 unsigned short* __restrict__ Klo) {
    int bt = blockIdx.x;
    int t  = bt & (T_ - 1);
    const float* row = Kf + (size_t)bt * C_;
    int i = threadIdx.x;
    float x1 = row[i], x2 = row[i + HALF_];
    float cv = cosT[t*HALF_ + i], sv = sinT[t*HALF_ + i];
    float v1 = x1*cv - x2*sv;
    float v2 = x2*cv + x1*sv;
    size_t o = (size_t)bt * C_ + i;
    unsigned short h1 = f2bf(v1), h2 = f2bf(v2);
    Khi[o]         = h1;
    Khi[o + HALF_] = h2;
    Klo[o]         = f2bf(v1 - bf2f(h1));
    Klo[o + HALF_] = f2bf(v2 - bf2f(h2));
}

// ---------------- QK + routing pass ----------------
// grid dense (b, tt:64, st:16); active iff st*128 <= tt*32+31.
// A rows R = t_local*4 + n (128), B rows = s (128), K = 512, split-bf16 3-MFMA.
__global__ __launch_bounds__(256) void qk_routing_k(
    const unsigned short* __restrict__ Qhi, const unsigned short* __restrict__ Qlo,
    const unsigned short* __restrict__ Khi, const unsigned short* __restrict__ Klo,
    unsigned short* __restrict__ P, float* __restrict__ partS, unsigned* __restrict__ partA)
{
    __shared__ __align__(16) char smem[65536];
    short* Ah = (short*)smem;
    short* Bh = Ah + 8192;
    short* Al = Bh + 8192;
    short* Bl = Bh + 16384;

    int tid = threadIdx.x;
    int w = tid >> 6, l = tid & 63;
    int wm = w >> 1, wn = w & 1;
    int llo = l & 15, lhi = l >> 4;
    int rl = l >> 3, gs = l & 7;
    int rb = w << 5;
    int bid = blockIdx.x;
    int st = bid & 15, tt = (bid >> 4) & 63, b = bid >> 10;
    int t0 = tt << 5, s0 = st << 7;
    if (s0 > t0 + 31) return;

    f32x4 acc[4][4];
    #pragma unroll
    for (int mi = 0; mi < 4; mi++)
        #pragma unroll
        for (int ni = 0; ni < 4; ni++) acc[mi][ni] = (f32x4){0.f,0.f,0.f,0.f};

    for (int k0 = 0; k0 < C_; k0 += 64) {
        #pragma unroll
        for (int i8 = 0; i8 < 4; i8++) {
            int r = rb + (i8 << 3) + rl;
            int sg = (gs ^ (r & 7)) << 3;
            int dsb = (rb + (i8 << 3)) * 64;
            size_t ga = (size_t)(b*T_ + t0 + (r >> 2)) * (NB_*C_) + ((r & 3) << 9) + k0 + sg;
            size_t gb = (size_t)(b*T_ + s0 + r) * C_ + k0 + sg;
            gl16(Qhi + ga, Ah + dsb);
            gl16(Qlo + ga, Al + dsb);
            gl16(Khi + gb, Bh + dsb);
            gl16(Klo + gb, Bl + dsb);
        }
        __syncthreads();
        #pragma unroll
        for (int ks = 0; ks < 2; ks++) {
            s16x8 bh[4], bl[4];
            #pragma unroll
            for (int ni = 0; ni < 4; ni++) {
                int br = (wn << 6) + (ni << 4) + llo;
                int bo = br*64 + ((((ks << 2) + lhi) ^ (br & 7)) << 3);
                bh[ni] = *(const s16x8*)&Bh[bo];
                bl[ni] = *(const s16x8*)&Bl[bo];
            }
            #pragma unroll
            for (int mi = 0; mi < 4; mi++) {
                int ar = (wm << 6) + (mi << 4) + llo;
                int ao = ar*64 + ((((ks << 2) + lhi) ^ (ar & 7)) << 3);
                s16x8 ah = *(const s16x8*)&Ah[ao];
                s16x8 al = *(const s16x8*)&Al[ao];
                #pragma unroll
                for (int ni = 0; ni < 4; ni++) {
                    acc[mi][ni] = __builtin_amdgcn_mfma_f32_16x16x32_bf16(ah, bh[ni], acc[mi][ni], 0, 0, 0);
                    acc[mi][ni] = __builtin_amdgcn_mfma_f32_16x16x32_bf16(ah, bl[ni], acc[mi][ni], 0, 0, 0);
                    acc[mi][ni] = __builtin_amdgcn_mfma_f32_16x16x32_bf16(al, bh[ni], acc[mi][ni], 0, 0, 0);
                }
            }
        }
        __syncthreads();
    }

    // ---- routing epilogue; P staged in LDS [4][32][136] (reuses smem) ----
    short* Pl = (short*)smem;
    #pragma unroll
    for (int mi = 0; mi < 4; mi++) {
        int tl = (wm << 4) + (mi << 2) + lhi;
        int tg = t0 + tl;
        float wsum = 0.f; unsigned ab = 0u;
        #pragma unroll
        for (int ni = 0; ni < 4; ni++) {
            int sl = (wn << 6) + (ni << 4) + llo;
            int sg = s0 + sl;
            f32x4 v = acc[mi][ni];
            float wu = 0.f; unsigned bits = 0u;
            if (sg <= tg) {
                float a0 = v[0]/SQRT_C, a1 = v[1]/SQRT_C, a2 = v[2]/SQRT_C, a3 = v[3]/SQRT_C;
                float m = fmaxf(fmaxf(a0, a1), fmaxf(a2, a3));
                float e0 = expf(a0-m), e1 = expf(a1-m), e2 = expf(a2-m), e3 = expf(a3-m);
                float sum = ((e0 + e1) + e2) + e3;
                float p0 = e0/sum, p1 = e1/sum, p2 = e2/sum, p3 = e3/sum;
                float mp = fmaxf(fmaxf(p0, p1), fmaxf(p2, p3));
                bits = (p0 == mp ? 1u : 0u) | (p1 == mp ? 2u : 0u)
                     | (p2 == mp ? 4u : 0u) | (p3 == mp ? 8u : 0u);
                wu = fmaxf(m, 0.f) + log1pf(expf(-fabsf(m)));
                wsum += wu; ab |= bits;
            }
            unsigned short wub = f2bf(wu);
            Pl[(0*32 + tl)*136 + sl] = (bits & 1u) ? (short)wub : (short)0;
            Pl[(1*32 + tl)*136 + sl] = (bits & 2u) ? (short)wub : (short)0;
            Pl[(2*32 + tl)*136 + sl] = (bits & 4u) ? (short)wub : (short)0;
            Pl[(3*32 + tl)*136 + sl] = (bits & 8u) ? (short)wub : (short)0;
        }
        #pragma unroll
        for (int mask = 1; mask <= 8; mask <<= 1) wsum += __shfl_xor(wsum, mask, 64);
        int ai = (int)ab;
        #pragma unroll
        for (int mask = 1; mask <= 8; mask <<= 1) ai |= __shfl_xor(ai, mask, 64);
        if (llo == 0) {
            size_t pidx = ((((size_t)(b*64 + tt) * 16 + st) * 2 + wn) * 32) + tl;
            partS[pidx] = wsum;
            partA[pidx] = (unsigned)ai;
        }
    }
    __syncthreads();
    // ---- copy P tile to global (coalesced 16B) ----
    for (int i = tid; i < 2048; i += 256) {
        int row = i >> 4, g8 = i & 15;
        int n = row >> 5, tl = row & 31;
        u16x8 v = *(const u16x8*)&Pl[row*136 + (g8 << 3)];
        *(u16x8*)(P + ((size_t)((b*4 + n)*T_ + t0 + tl)) * T_ + s0 + (g8 << 3)) = v;
    }
}

// ---------------- PV pass: y[b][t][c] = sum_n P_n @ V_n, 4-phase k-split ----------------
__global__ __launch_bounds__(256) void pv_k(
    const unsigned short* __restrict__ P, const unsigned short* __restrict__ Vt,
    float* __restrict__ py)
{
    __shared__ __align__(16) char smem[32768];
    short* Ah = (short*)smem;
    short* Bh = Ah + 8192;
    int tid = threadIdx.x;
    int w = tid >> 6, l = tid & 63;
    int wm = w >> 1, wn = w & 1;
    int llo = l & 15, lhi = l >> 4;
    int rl = l >> 3, gs = l & 7;
    int rb = w << 5;
    int bid = blockIdx.x;
    int ph = bid & 3, cc = (bid >> 2) & 3, tt = (bid >> 4) & 15, b = bid >> 8;
    int t0 = tt << 7, c0 = cc << 7;

    f32x4 acc[4][4];
    #pragma unroll
    for (int mi = 0; mi < 4; mi++)
        #pragma unroll
        for (int ni = 0; ni < 4; ni++) acc[mi][ni] = (f32x4){0.f,0.f,0.f,0.f};

    for (int n = 0; n < 4; n++) {
        for (int sb = ph * 128; sb <= t0 + 127; sb += 512) {
            #pragma unroll
            for (int h = 0; h < 2; h++) {
                int k0 = sb + h*64;
                #pragma unroll
                for (int i8 = 0; i8 < 4; i8++) {
                    int r = rb + (i8 << 3) + rl;
                    int sg = (gs ^ (r & 7)) << 3;
                    int dsb = (rb + (i8 << 3)) * 64;
                    gl16(P  + ((size_t)((b*4 + n)*T_ + t0 + r)) * T_ + k0 + sg, Ah + dsb);
                    gl16(Vt + ((size_t)(b*(NB_*C_) + (n << 9) + c0 + r)) * T_ + k0 + sg, Bh + dsb);
                }
                __syncthreads();
                #pragma unroll
                for (int ks = 0; ks < 2; ks++) {
                    s16x8 bh[4];
                    #pragma unroll
                    for (int ni = 0; ni < 4; ni++) {
                        int br = (wn << 6) + (ni << 4) + llo;
                        bh[ni] = *(const s16x8*)&Bh[br*64 + ((((ks << 2) + lhi) ^ (br & 7)) << 3)];
                    }
                    #pragma unroll
                    for (int mi = 0; mi < 4; mi++) {
                        int ar = (wm << 6) + (mi << 4) + llo;
                        s16x8 ah = *(const s16x8*)&Ah[ar*64 + ((((ks << 2) + lhi) ^ (ar & 7)) << 3)];
                        #pragma unroll
                        for (int ni = 0; ni < 4; ni++)
                            acc[mi][ni] = __builtin_amdgcn_mfma_f32_16x16x32_bf16(ah, bh[ni], acc[mi][ni], 0, 0, 0);
                    }
                }
                __syncthreads();
            }
        }
    }
    float* out = py + (size_t)ph * (BT_*(size_t)C_);
    #pragma unroll
    for (int mi = 0; mi < 4; mi++) {
        int row0 = t0 + (wm << 6) + (mi << 4) + (lhi << 2);
        #pragma unroll
        for (int ni = 0; ni < 4; ni++) {
            int col = c0 + (wn << 6) + (ni << 4) + llo;
            f32x4 v = acc[mi][ni];
            #pragma unroll
            for (int r = 0; r < 4; r++)
                out[(size_t)(b*T_ + row0 + r) * C_ + col] = v[r];
        }
    }
}

// ---------------- combine: y partials + S/act + sinks -> ybf16 ----------------
__global__ __launch_bounds__(256) void combine3_k(
    const float* __restrict__ py, const float* __restrict__ partS,
    const unsigned* __restrict__ partA,
    const float* __restrict__ basis, const float* __restrict__ resid_sink,
    unsigned short* __restrict__ ybf)
{
    int bt = blockIdx.x;
    int t = bt & (T_ - 1);
    int b = bt >> 11;
    int i = threadIdx.x;
    int tt32 = t >> 5, tl = t & 31;
    int stmax = tt32 >> 2;
    float S = 0.f; unsigned act = 0u;
    for (int st = 0; st <= stmax; st++) {
        #pragma unroll
        for (int wn = 0; wn < 2; wn++) {
            size_t idx = ((((size_t)(b*64 + tt32) * 16 + st) * 2 + wn) * 32) + tl;
            S += partS[idx];
            act |= partA[idx];
        }
    }
    float y0 = 0.f, y1 = 0.f;
    #pragma unroll
    for (int ph = 0; ph < 4; ph++) {
        y0 += py[(size_t)ph * (BT_*(size_t)C_) + (size_t)bt * C_ + i];
        y1 += py[(size_t)ph * (BT_*(size_t)C_) + (size_t)bt * C_ + i + 256];
    }
    float scale = fminf(1.0f / (S + 1e-6f), 1.0f);
    float residual = 1.0f - scale * S;
    if (t < T_ - 1) act = 0xFu;
    float o0 = scale * y0, o1 = scale * y1;
    #pragma unroll
    for (int n = 0; n < 4; n++) if ((act >> n) & 1u) {
        o0 += basis[n*C_ + i];
        o1 += basis[n*C_ + i + 256];
    }
    o0 += residual * resid_sink[i];
    o1 += residual * resid_sink[i + 256];
    ybf[(size_t)bt * C_ + i]       = f2bf(o0);
    ybf[(size_t)bt * C_ + i + 256] = f2bf(o1);
}

extern "C" void kernel_launch(void* const* d_in, const int* in_sizes, int n_in,
                              void* d_out, int out_size, void* d_ws, size_t ws_size,
                              hipStream_t stream) {
    const float* a    = (const float*)d_in[0];
    const float* x    = (const float*)d_in[1];
    const float* Wq   = (const float*)d_in[2];
    const float* Wk   = (const float*)d_in[3];
    const float* Wv   = (const float*)d_in[4];
    const float* Wo   = (const float*)d_in[5];
    const float* vres = (const float*)d_in[6];
    const float* vbas = (const float*)d_in[7];

    float* ws = (float*)d_ws;
    float* cosT = ws;                              // 524288 f
    float* sinT = cosT + 524288;                   // 524288 f
    float* Qf   = sinT + 524288;                   // 8388608 f (reused as py)
    float* Kf   = Qf + 8388608;                    // 2097152 f (reused: partS/partA/ybf)
    unsigned short* ahi  = (unsigned short*)(Kf + 2097152);
    unsigned short* alo  = ahi  + 2097152;
    unsigned short* xhi  = alo  + 2097152;
    unsigned short* xlo  = xhi  + 2097152;
    unsigned short* Wqth = xlo  + 2097152;
    unsigned short* Wqtl = Wqth + 1048576;
    unsigned short* Wkth = Wqtl + 1048576;
    unsigned short* Wktl = Wkth + 262144;
    unsigned short* Wvth = Wktl + 262144;
    unsigned short* Woth = Wvth + 1048576;
    unsigned short* Qhi  = Woth + 262144;
    unsigned short* Qlo  = Qhi  + 8388608;
    unsigned short* Khi  = Qlo  + 8388608;
    unsigned short* Klo  = Khi  + 2097152;
    unsigned short* Vt   = Klo  + 2097152;
    unsigned short* P    = Vt   + 8388608;         // 33554432 shorts

    float* py = Qf;
    float* partS = Kf;
    unsigned* partA = (unsigned*)(Kf + 131072);
    unsigned short* ybf = (unsigned short*)(Kf + 262144);

    rope_table_k<<<T_, 256, 0, stream>>>(cosT, sinT);
    cast2_hilo_k<<<4096, 256, 0, stream>>>(a, x, ahi, alo, xhi, xlo);
    tcast_k<<<256, 256, 0, stream>>>(Wq, Wqth, Wqtl, 512, 2048, 1);
    tcast_k<<<64,  256, 0, stream>>>(Wk, Wkth, Wktl, 512, 512,  1);
    tcast_k<<<256, 256, 0, stream>>>(Wv, Wvth, nullptr, 512, 2048, 0);
    tcast_k<<<64,  256, 0, stream>>>(Wo, Woth, nullptr, 512, 512,  0);

    mm_k<1><<<512, 256, 0, stream>>>(ahi, alo, Wqth, Wqtl, Qf, BT_, 2048, 512);
    mm_k<1><<<128, 256, 0, stream>>>(xhi, xlo, Wkth, Wktl, Kf, BT_, 512, 512);
    mm_v_k<<<512, 256, 0, stream>>>(ahi, Wvth, Vt, BT_, 2048, 512);

    q_post2_k<<<BT_*NB_, 256, 0, stream>>>(Qf, cosT, sinT, Qhi, Qlo);
    k_post2_k<<<BT_,     256, 0, stream>>>(Kf, cosT, sinT, Khi, Klo);

    qk_routing_k<<<2048, 256, 0, stream>>>(Qhi, Qlo, Khi, Klo, P, partS, partA);
    pv_k<<<512, 256, 0, stream>>>(P, Vt, py);
    combine3_k<<<BT_, 256, 0, stream>>>(py, partS, partA, vbas, vres, ybf);

    mm_k<0><<<128, 256, 0, stream>>>(ybf, nullptr, Woth, nullptr, (float*)d_out, BT_, 512, 512);
}